// Round 2
// baseline (391.398 us; speedup 1.0000x reference)
//
#include <hip/hip_runtime.h>
#include <hip/hip_bf16.h>
#include <cstddef>

// Problem constants (fixed by setup_inputs)
#define T_TOK 512
#define NH    12
#define HD    64
#define NV    32000
#define CEMB  768
#define NC    20          // vocab chunks (480 blocks = single dispatch round)
#define VC    (NV/NC)     // 1600 rows per chunk
#define NSUB  (VC/64)     // 25 subtiles of 64 rows
#define QTILE 256         // queries per block (2 q-groups cover T=512)
#define LOG2E 1.44269504088896340736f

typedef short v8bf __attribute__((ext_vector_type(8)));   // 8 bf16 = 4 VGPRs
typedef float v4f  __attribute__((ext_vector_type(4)));   // MFMA C/D

__device__ __forceinline__ unsigned short f2bf(float f) {
    unsigned u = __float_as_uint(f);
    u += 0x7fffu + ((u >> 16) & 1u);            // RNE
    return (unsigned short)(u >> 16);
}
// v_cvt_pk_bf16_f32: lo=bf16(a), hi=bf16(b), RNE — 1 instr vs ~9 emulated.
__device__ __forceinline__ unsigned cvtpk(float a, float b) {
    unsigned r;
    asm("v_cvt_pk_bf16_f32 %0, %1, %2" : "=v"(r) : "v"(a), "v"(b));
    return r;
}
__device__ __forceinline__ float bf2f(unsigned short u) {
    return __uint_as_float(((unsigned)u) << 16);
}
// async global->LDS, 16B/lane; LDS dst = wave-uniform base + lane*16
__device__ __forceinline__ void gld16(const void* g, void* l) {
    __builtin_amdgcn_global_load_lds(
        (const __attribute__((address_space(1))) unsigned*)g,
        (__attribute__((address_space(3))) unsigned*)l, 16, 0, 0);
}

// ---------------------------------------------------------------------------
// Kernel 0: Wv (H,V,D) fp32 -> bf16, pure streaming cast (RNE, bit-identical
// to the previous in-loop conversion). Lets flash stage K via global_load_lds.
// ---------------------------------------------------------------------------
__global__ __launch_bounds__(256) void wv_to_bf16(const float* __restrict__ Wv,
                                                  unsigned short* __restrict__ Wb) {
    const size_t i = ((size_t)blockIdx.x*256 + threadIdx.x) * 8;
    float4 a = *(const float4*)&Wv[i];
    float4 b = *(const float4*)&Wv[i+4];
    uint4 w = { cvtpk(a.x, a.y), cvtpk(a.z, a.w),
                cvtpk(b.x, b.y), cvtpk(b.z, b.w) };
    *(uint4*)&Wb[i] = w;
}

// ---------------------------------------------------------------------------
// Kernel 1: Qb[h][t][d] (bf16) = (x . W_ffn^T + b) * LOG2E / tau  (fp32 math)
// ---------------------------------------------------------------------------
__global__ __launch_bounds__(256) void ffn_kernel(
        const float* __restrict__ x, const float* __restrict__ Wf,
        const float* __restrict__ bf, const float* __restrict__ temps,
        unsigned short* __restrict__ Qb) {
    const int h = blockIdx.y;
    const int tl = threadIdx.x >> 6, e = threadIdx.x & 63;
    const int t = blockIdx.x * 4 + tl;
    __shared__ float xs[4][HD];
    xs[tl][e] = x[t*CEMB + h*HD + e];
    __syncthreads();
    const float4* w4  = (const float4*)(Wf + (size_t)(h*HD + e)*HD);
    const float4* xs4 = (const float4*)xs[tl];
    float acc = bf[h*HD + e];
    #pragma unroll
    for (int i = 0; i < HD/4; ++i) {
        float4 a = xs4[i], b = w4[i];
        acc += a.x*b.x + a.y*b.y + a.z*b.z + a.w*b.w;
    }
    float tau = temps[h]; tau = (tau < 0.1f) ? 0.1f : tau;
    Qb[((size_t)h*T_TOK + t)*HD + e] = f2bf(acc * LOG2E / tau);
}

// ---------------------------------------------------------------------------
// Kernel 2: E (V,768) fp32  ->  ET[h][d][v] bf16 (v contiguous), per 64-v tile.
// ---------------------------------------------------------------------------
__global__ __launch_bounds__(256) void e_transpose(const float* __restrict__ E,
                                                   unsigned short* __restrict__ ET) {
    const int v0 = blockIdx.x * 64, h = blockIdx.y;
    const int tid = threadIdx.x;
    __shared__ float Ts[64*65];                 // [d][v], stride 65
    #pragma unroll
    for (int r = 0; r < 4; ++r) {
        int f = tid + 256*r, v = f >> 4, d4 = f & 15;
        float4 e4 = *(const float4*)&E[(size_t)(v0 + v)*CEMB + h*HD + d4*4];
        Ts[(d4*4+0)*65 + v] = e4.x;
        Ts[(d4*4+1)*65 + v] = e4.y;
        Ts[(d4*4+2)*65 + v] = e4.z;
        Ts[(d4*4+3)*65 + v] = e4.w;
    }
    __syncthreads();
    #pragma unroll
    for (int r = 0; r < 2; ++r) {
        int u = tid + 256*r, d = u >> 3, c16 = u & 7;
        const float* row = &Ts[d*65 + c16*8];
        uint4 w;
        w.x = cvtpk(row[0], row[1]);
        w.y = cvtpk(row[2], row[3]);
        w.z = cvtpk(row[4], row[5]);
        w.w = cvtpk(row[6], row[7]);
        *(uint4*)&ET[(size_t)(h*64 + d)*NV + v0 + c16*8] = w;
    }
}

// ---------------------------------------------------------------------------
// Kernel 3: MFMA flash. 8 waves x 32 q-rows (512 thr), single barrier/subtile,
// dbuf K/E both staged via global_load_lds (K pre-converted to bf16).
// LDS swizzle (per 64x64 bf16 tile, stride 64): 16B-group g of row r lives at
// group (g ^ (r&7)); achieved by pre-swizzling the per-lane GLOBAL source
// column while keeping the LDS destination linear (guide §5 caveat).
// Grid = NC*2*NH = 480 blocks <= 512 capacity (2 blocks/CU @ 64KB LDS):
// single dispatch round, no tail, 16 waves/CU resident.
// ---------------------------------------------------------------------------
__global__ __launch_bounds__(512, 4) void flash_mfma(
        const unsigned short* __restrict__ Qb, const unsigned short* __restrict__ Wb,
        const unsigned short* __restrict__ ET, unsigned short* __restrict__ Npart,
        float* __restrict__ Zpart) {
    const int c = blockIdx.x, qg = blockIdx.y, h = blockIdx.z;
    const int tid  = threadIdx.x;
    const int wq   = tid >> 6;        // wave id 0..7: q range [wq*32, wq*32+32)
    const int lane = tid & 63;
    const int l15  = lane & 15, quad = lane >> 4;
    const int X    = l15 & 7;         // row-swizzle key for fragment reads

    __shared__ unsigned short Kb[2][64*64];   // K subtile  [v][d], swizzled
    __shared__ unsigned short Eb[2][64*64];   // E^T subtile [d][v], swizzled
    __shared__ unsigned short Ps[QTILE*64];   // P=exp2(S') [q][v], wave-private rows

    const int tbase = qg*QTILE + wq*32;

    // ---- Q fragments (B-operand): lane holds Q[q=nt*16+l15][d=kb*32+quad*8..+7]
    v8bf qf[2][2];
    #pragma unroll
    for (int nt = 0; nt < 2; ++nt)
        #pragma unroll
        for (int kb = 0; kb < 2; ++kb)
            qf[nt][kb] = *(const v8bf*)&Qb[((size_t)h*T_TOK + tbase + nt*16 + l15)*HD
                                           + kb*32 + quad*8];

    v4f o[4][2];
    #pragma unroll
    for (int mt = 0; mt < 4; ++mt)
        #pragma unroll
        for (int nt = 0; nt < 2; ++nt) { v4f z = {0.f,0.f,0.f,0.f}; o[mt][nt] = z; }
    float zacc[2] = {0.f, 0.f};

    // ---- staging addressing (loop-invariant): each wave stages 8 rows of K
    // and 8 rows of E per subtile with ONE gld16 each (64 lanes x 16B = 8x128B).
    const int rsub = lane >> 3;                    // row within wave's 8
    const int Gv   = (lane & 7) ^ rsub;            // pre-swizzled source group
    const unsigned short* kg = Wb + ((size_t)h*NV + (size_t)c*VC + wq*8 + rsub)*HD + Gv*8;
    const unsigned short* eg = ET + ((size_t)(h*64 + wq*8 + rsub))*NV + (size_t)c*VC + Gv*8;
    unsigned short* kld = &Kb[0][(wq*8)*64];   // +32768B for buf 1 (handled via array)
    unsigned short* eld = &Eb[0][(wq*8)*64];

    // ---- prologue: stage subtile 0 into buf 0 ----
    gld16(kg, &Kb[0][(wq*8)*64]);
    gld16(eg, &Eb[0][(wq*8)*64]);
    __syncthreads();

    int nb = 1;                                  // buffer being filled
    for (int s = 0; s < NSUB; ++s) {
        const int cur = nb ^ 1;                  // buffer being computed on
        const bool pre = (s + 1 < NSUB);
        if (pre) {
            gld16(kg + (size_t)(s+1)*4096, &Kb[nb][(wq*8)*64]);   // 64 rows x 64 elems
            gld16(eg + (s+1)*64,           &Eb[nb][(wq*8)*64]);
        }

        // ---- phase A: S'^T = K.Q^T (log2 domain), P = exp2 ----
        v8bf kf[4][2];
        #pragma unroll
        for (int mt = 0; mt < 4; ++mt) {
            const int row = (mt*16 + l15)*64;
            kf[mt][0] = *(const v8bf*)&Kb[cur][row + ((quad     ^ X))*8];
            kf[mt][1] = *(const v8bf*)&Kb[cur][row + (((4+quad) ^ X))*8];
        }
        #pragma unroll
        for (int nt = 0; nt < 2; ++nt) {
            #pragma unroll
            for (int mt = 0; mt < 4; ++mt) {
                v4f sa = {0.f,0.f,0.f,0.f};
                sa = __builtin_amdgcn_mfma_f32_16x16x32_bf16(kf[mt][0], qf[nt][0], sa, 0, 0, 0);
                sa = __builtin_amdgcn_mfma_f32_16x16x32_bf16(kf[mt][1], qf[nt][1], sa, 0, 0, 0);
                float p0 = exp2f(sa[0]), p1 = exp2f(sa[1]);
                float p2 = exp2f(sa[2]), p3 = exp2f(sa[3]);
                zacc[nt] += (p0 + p1) + (p2 + p3);
                uint2 w = { cvtpk(p0, p1), cvtpk(p2, p3) };
                const int q = wq*32 + nt*16 + l15;
                *(uint2*)&Ps[q*64 + (((mt*2 + (quad>>1)) ^ X))*8 + (quad&1)*4] = w;
            }
        }

        // ---- phase B: O^T += E^T . P (Ps rows wave-private, no barrier) ----
        v8bf ef[4][2];
        #pragma unroll
        for (int mt = 0; mt < 4; ++mt) {
            const int row = (mt*16 + l15)*64;
            ef[mt][0] = *(const v8bf*)&Eb[cur][row + ((quad     ^ X))*8];
            ef[mt][1] = *(const v8bf*)&Eb[cur][row + (((4+quad) ^ X))*8];
        }
        __builtin_amdgcn_s_setprio(1);
        #pragma unroll
        for (int nt = 0; nt < 2; ++nt) {
            const int q = wq*32 + nt*16 + l15;
            v8bf pf0 = *(const v8bf*)&Ps[q*64 + ((quad     ^ X))*8];
            v8bf pf1 = *(const v8bf*)&Ps[q*64 + (((4+quad) ^ X))*8];
            #pragma unroll
            for (int mt = 0; mt < 4; ++mt) {
                o[mt][nt] = __builtin_amdgcn_mfma_f32_16x16x32_bf16(ef[mt][0], pf0, o[mt][nt], 0, 0, 0);
                o[mt][nt] = __builtin_amdgcn_mfma_f32_16x16x32_bf16(ef[mt][1], pf1, o[mt][nt], 0, 0, 0);
            }
        }
        __builtin_amdgcn_s_setprio(0);

        if (pre) __syncthreads();   // drains prefetch issued a full phase ago
        nb ^= 1;
    }

    // ---- Z: reduce across quads ----
    #pragma unroll
    for (int nt = 0; nt < 2; ++nt) {
        float z = zacc[nt];
        z += __shfl_xor(z, 16, 64);
        z += __shfl_xor(z, 32, 64);
        if (quad == 0)
            Zpart[((size_t)c*T_TOK + tbase + nt*16 + l15)*NH + h] = z;
    }
    // ---- store O^T as bf16 (lane has 4 consecutive d per (mt,nt)) ----
    #pragma unroll
    for (int nt = 0; nt < 2; ++nt) {
        const int t = tbase + nt*16 + l15;
        unsigned short* np = Npart + (((size_t)c*T_TOK + t)*NH + h)*HD;
        #pragma unroll
        for (int mt = 0; mt < 4; ++mt) {
            v4f ov = o[mt][nt];
            uint2 w = { cvtpk(ov[0], ov[1]), cvtpk(ov[2], ov[3]) };
            *(uint2*)&np[mt*16 + quad*4] = w;
        }
    }
    (void)kld; (void)eld;
}

// ---------------------------------------------------------------------------
// Kernel 4: out[t, h*64+d] = sum_c N[c,t,h,d] / sum_c Z[c,t,h]   (4 elems/thr)
// ---------------------------------------------------------------------------
__global__ void combine_kernel(const unsigned short* __restrict__ Npart,
                               const float* __restrict__ Zpart,
                               float* __restrict__ out) {
    const int idx = (blockIdx.x*256 + threadIdx.x)*4;  // over T_TOK*CEMB
    const int t = idx / CEMB;
    const int rem = idx % CEMB;
    const int h = rem >> 6, d = rem & 63;
    float n0 = 0.f, n1 = 0.f, n2 = 0.f, n3 = 0.f, z = 0.f;
    #pragma unroll
    for (int c = 0; c < NC; ++c) {
        uint2 u = *(const uint2*)&Npart[(((size_t)c*T_TOK + t)*NH + h)*HD + d];
        n0 += bf2f((unsigned short)(u.x & 0xffffu));
        n1 += bf2f((unsigned short)(u.x >> 16));
        n2 += bf2f((unsigned short)(u.y & 0xffffu));
        n3 += bf2f((unsigned short)(u.y >> 16));
        z  += Zpart[((size_t)c*T_TOK + t)*NH + h];
    }
    const float rz = 1.0f / z;
    float4 o = { n0*rz, n1*rz, n2*rz, n3*rz };
    *(float4*)&out[idx] = o;
}

extern "C" void kernel_launch(void* const* d_in, const int* in_sizes, int n_in,
                              void* d_out, int out_size, void* d_ws, size_t ws_size,
                              hipStream_t stream) {
    const float* x     = (const float*)d_in[0];
    const float* Wf    = (const float*)d_in[1];
    const float* bf    = (const float*)d_in[2];
    const float* Wv    = (const float*)d_in[3];
    const float* temps = (const float*)d_in[4];
    const float* E     = (const float*)d_in[5];
    float* out = (float*)d_out;

    // workspace layout (bytes):
    //   Npart bf16: NC*512*12*64*2  = 15,728,640
    //   Zpart f32 : NC*512*12*4     =    491,520
    //   Qb    bf16: 12*512*64*2     =    786,432
    //   ET    bf16: 12*64*32000*2   = 49,152,000
    //   Wb    bf16: 12*32000*64*2   = 49,152,000   (total ~115.3 MB)
    char* ws = (char*)d_ws;
    unsigned short* Npart = (unsigned short*)ws;
    float*          Zpart = (float*)(ws + 15728640);
    unsigned short* Qb    = (unsigned short*)(ws + 16220160);
    unsigned short* ET    = (unsigned short*)(ws + 17006592);
    unsigned short* Wb    = (unsigned short*)(ws + 66158592);

    wv_to_bf16    <<<dim3((NH*NV*HD)/2048),     256, 0, stream>>>(Wv, Wb);
    e_transpose   <<<dim3(NV/64, NH),           256, 0, stream>>>(E, ET);
    ffn_kernel    <<<dim3(T_TOK/4, NH),         256, 0, stream>>>(x, Wf, bf, temps, Qb);
    flash_mfma    <<<dim3(NC, T_TOK/QTILE, NH), 512, 0, stream>>>(Qb, Wb, ET, Npart, Zpart);
    combine_kernel<<<dim3((T_TOK*CEMB)/1024),   256, 0, stream>>>(Npart, Zpart, out);
}

// Round 3
// 314.099 us; speedup vs baseline: 1.2461x; 1.2461x over previous
//
#include <hip/hip_runtime.h>
#include <hip/hip_bf16.h>
#include <cstddef>

// Problem constants (fixed by setup_inputs)
#define T_TOK 512
#define NH    12
#define HD    64
#define NV    32000
#define CEMB  768
#define NC    20          // vocab chunks: grid = NC*2*NH = 480 = single round
#define VC    (NV/NC)     // 1600 rows per chunk
#define NSUB  (VC/64)     // 25 subtiles of 64 rows
#define QTILE 256         // queries per block (2 q-groups cover T=512)
#define LOG2E 1.44269504088896340736f

typedef short v8bf __attribute__((ext_vector_type(8)));   // 8 bf16 = 4 VGPRs
typedef float v4f  __attribute__((ext_vector_type(4)));   // MFMA C/D

__device__ __forceinline__ unsigned short f2bf(float f) {
    unsigned u = __float_as_uint(f);
    u += 0x7fffu + ((u >> 16) & 1u);            // RNE
    return (unsigned short)(u >> 16);
}
// v_cvt_pk_bf16_f32: lo=bf16(a), hi=bf16(b), RNE — 1 instr vs ~9 emulated.
__device__ __forceinline__ unsigned cvtpk(float a, float b) {
    unsigned r;
    asm("v_cvt_pk_bf16_f32 %0, %1, %2" : "=v"(r) : "v"(a), "v"(b));
    return r;
}
__device__ __forceinline__ float bf2f(unsigned short u) {
    return __uint_as_float(((unsigned)u) << 16);
}
// async global->LDS, 16B/lane; LDS dst = wave-uniform base + lane*16
__device__ __forceinline__ void gld16(const void* g, void* l) {
    __builtin_amdgcn_global_load_lds(
        (const __attribute__((address_space(1))) unsigned*)g,
        (__attribute__((address_space(3))) unsigned*)l, 16, 0, 0);
}

// ---------------------------------------------------------------------------
// Kernel 1: Qb[h][t][d] (bf16) = (x . W_ffn^T + b) * LOG2E / tau  (fp32 math)
// ---------------------------------------------------------------------------
__global__ __launch_bounds__(256) void ffn_kernel(
        const float* __restrict__ x, const float* __restrict__ Wf,
        const float* __restrict__ bf, const float* __restrict__ temps,
        unsigned short* __restrict__ Qb) {
    const int h = blockIdx.y;
    const int tl = threadIdx.x >> 6, e = threadIdx.x & 63;
    const int t = blockIdx.x * 4 + tl;
    __shared__ float xs[4][HD];
    xs[tl][e] = x[t*CEMB + h*HD + e];
    __syncthreads();
    const float4* w4  = (const float4*)(Wf + (size_t)(h*HD + e)*HD);
    const float4* xs4 = (const float4*)xs[tl];
    float acc = bf[h*HD + e];
    #pragma unroll
    for (int i = 0; i < HD/4; ++i) {
        float4 a = xs4[i], b = w4[i];
        acc += a.x*b.x + a.y*b.y + a.z*b.z + a.w*b.w;
    }
    float tau = temps[h]; tau = (tau < 0.1f) ? 0.1f : tau;
    Qb[((size_t)h*T_TOK + t)*HD + e] = f2bf(acc * LOG2E / tau);
}

// ---------------------------------------------------------------------------
// Kernel 2: E (V,768) fp32  ->  ET[h][d][v] bf16 (v contiguous), per 64-v tile.
// ---------------------------------------------------------------------------
__global__ __launch_bounds__(256) void e_transpose(const float* __restrict__ E,
                                                   unsigned short* __restrict__ ET) {
    const int v0 = blockIdx.x * 64, h = blockIdx.y;
    const int tid = threadIdx.x;
    __shared__ float Ts[64*65];                 // [d][v], stride 65
    #pragma unroll
    for (int r = 0; r < 4; ++r) {
        int f = tid + 256*r, v = f >> 4, d4 = f & 15;
        float4 e4 = *(const float4*)&E[(size_t)(v0 + v)*CEMB + h*HD + d4*4];
        Ts[(d4*4+0)*65 + v] = e4.x;
        Ts[(d4*4+1)*65 + v] = e4.y;
        Ts[(d4*4+2)*65 + v] = e4.z;
        Ts[(d4*4+3)*65 + v] = e4.w;
    }
    __syncthreads();
    #pragma unroll
    for (int r = 0; r < 2; ++r) {
        int u = tid + 256*r, d = u >> 3, c16 = u & 7;
        const float* row = &Ts[d*65 + c16*8];
        uint4 w;
        w.x = cvtpk(row[0], row[1]);
        w.y = cvtpk(row[2], row[3]);
        w.z = cvtpk(row[4], row[5]);
        w.w = cvtpk(row[6], row[7]);
        *(uint4*)&ET[(size_t)(h*64 + d)*NV + v0 + c16*8] = w;
    }
}

// ---------------------------------------------------------------------------
// Kernel 3: MFMA flash (R1-proven structure). 4 waves x 64 q-rows, single
// barrier/subtile, dbuf K/E, XOR-swizzled LDS. E staged via global_load_lds;
// K (fp32 in HBM) prefetched to VGPRs at loop top, cvt+ds_write at loop bottom.
// Grid: 1D 480 blocks, remapped so the two qg-blocks of each (c,h) are exactly
// 8 linear ids apart -> same XCD, adjacent slots -> second stream hits that
// XCD's L2 (chunk 615 KB << 4 MB) instead of a duplicate concurrent HBM miss.
// ---------------------------------------------------------------------------
__global__ __launch_bounds__(256, 2) void flash_mfma(
        const unsigned short* __restrict__ Qb, const float* __restrict__ Wv,
        const unsigned short* __restrict__ ET, unsigned short* __restrict__ Npart,
        float* __restrict__ Zpart) {
    // ---- XCD-pairing remap: g and g+8 share (c,h), differ in qg ----
    const int g    = blockIdx.x;          // 0..479
    const int xcd  = g & 7, slot = g >> 3;  // slot 0..59
    const int qg   = slot & 1;
    const int p    = (slot >> 1)*8 + xcd;   // pair index 0..239
    const int c    = p % NC;
    const int h    = p / NC;

    const int tid  = threadIdx.x;
    const int wq   = tid >> 6;        // wave id: q range [wq*64, wq*64+64)
    const int lane = tid & 63;
    const int l15  = lane & 15, quad = lane >> 4;
    const int X    = l15 & 7;         // row-swizzle key for fragment reads

    __shared__ unsigned short Kb[2][64*64];   // K subtile  [v][d], swizzled
    __shared__ unsigned short Eb[2][64*64];   // E^T subtile [d][v], swizzled
    __shared__ unsigned short Ps[QTILE*64];   // P=exp2(S') [q][v], wave-private rows

    const int tbase = qg*QTILE + wq*64;

    // ---- Q fragments (B-operand): lane holds Q[q=nt*16+l15][d=kb*32+quad*8..+7]
    v8bf qf[4][2];
    #pragma unroll
    for (int nt = 0; nt < 4; ++nt)
        #pragma unroll
        for (int kb = 0; kb < 2; ++kb)
            qf[nt][kb] = *(const v8bf*)&Qb[((size_t)h*T_TOK + tbase + nt*16 + l15)*HD
                                           + kb*32 + quad*8];

    v4f o[4][4];
    #pragma unroll
    for (int mt = 0; mt < 4; ++mt)
        #pragma unroll
        for (int nt = 0; nt < 4; ++nt) { v4f z = {0.f,0.f,0.f,0.f}; o[mt][nt] = z; }
    float zacc[4] = {0.f, 0.f, 0.f, 0.f};

    // ---- staging addressing (loop-invariant per lane) ----
    // K: wave stages rows kv = wq*16 + (lane>>2); 4 float4 loads, f4 = (lane&3)+4r
    const int kv = wq*16 + (lane >> 2);
    const int Xk = kv & 7;
    const float* kgl = Wv + ((size_t)h*NV + (size_t)c*VC + kv)*HD + (lane & 3)*4;
    int kwoff[4];
    #pragma unroll
    for (int r = 0; r < 4; ++r)
        kwoff[r] = kv*64 + (((((lane&3)>>1) + 2*r) ^ Xk))*8 + (lane&1)*4;
    // E: 2 DMA instr/wave: rows d = wq*16 + i*8 + (lane>>3), col-group Gv = (lane&7)^(lane>>3)
    const int Gv = (lane & 7) ^ (lane >> 3);
    const unsigned short* eg0 = ET + (size_t)(h*64 + wq*16 + (lane >> 3))*NV
                                   + (size_t)c*VC + Gv*8;
    const unsigned short* eg1 = eg0 + (size_t)8*NV;

    // ---- prologue: stage subtile 0 into buf 0 ----
    {
        gld16(eg0, &Eb[0][(wq*16)*64]);
        gld16(eg1, &Eb[0][(wq*16 + 8)*64]);
        float4 k0[4];
        #pragma unroll
        for (int r = 0; r < 4; ++r) k0[r] = *(const float4*)(kgl + r*16);
        #pragma unroll
        for (int r = 0; r < 4; ++r) {
            uint2 w = { cvtpk(k0[r].x, k0[r].y), cvtpk(k0[r].z, k0[r].w) };
            *(uint2*)&Kb[0][kwoff[r]] = w;
        }
        __syncthreads();
    }

    int nb = 1;                                  // buffer being filled
    for (int s = 0; s < NSUB; ++s) {
        const int cur = nb ^ 1;                  // buffer being computed on
        const bool pre = (s + 1 < NSUB);
        float4 kr[4];
        if (pre) {
            gld16(eg0 + (s+1)*64, &Eb[nb][(wq*16)*64]);
            gld16(eg1 + (s+1)*64, &Eb[nb][(wq*16 + 8)*64]);
            #pragma unroll
            for (int r = 0; r < 4; ++r)
                kr[r] = *(const float4*)(kgl + (size_t)(s+1)*4096 + r*16);
        }

        // ---- phase A: S'^T = K.Q^T (log2 domain), P = exp2 ----
        v8bf kf[4][2];
        #pragma unroll
        for (int mt = 0; mt < 4; ++mt) {
            const int row = (mt*16 + l15)*64;
            kf[mt][0] = *(const v8bf*)&Kb[cur][row + ((quad     ^ X))*8];
            kf[mt][1] = *(const v8bf*)&Kb[cur][row + (((4+quad) ^ X))*8];
        }
        #pragma unroll
        for (int nt = 0; nt < 4; ++nt) {
            #pragma unroll
            for (int mt = 0; mt < 4; ++mt) {
                v4f sa = {0.f,0.f,0.f,0.f};
                sa = __builtin_amdgcn_mfma_f32_16x16x32_bf16(kf[mt][0], qf[nt][0], sa, 0, 0, 0);
                sa = __builtin_amdgcn_mfma_f32_16x16x32_bf16(kf[mt][1], qf[nt][1], sa, 0, 0, 0);
                float p0 = exp2f(sa[0]), p1 = exp2f(sa[1]);
                float p2 = exp2f(sa[2]), p3 = exp2f(sa[3]);
                zacc[nt] += (p0 + p1) + (p2 + p3);
                uint2 w = { cvtpk(p0, p1), cvtpk(p2, p3) };
                const int q = wq*64 + nt*16 + l15;
                *(uint2*)&Ps[q*64 + (((mt*2 + (quad>>1)) ^ X))*8 + (quad&1)*4] = w;
            }
        }

        // ---- phase B: O^T += E^T . P (Ps rows wave-private, no barrier) ----
        v8bf ef[4][2];
        #pragma unroll
        for (int mt = 0; mt < 4; ++mt) {
            const int row = (mt*16 + l15)*64;
            ef[mt][0] = *(const v8bf*)&Eb[cur][row + ((quad     ^ X))*8];
            ef[mt][1] = *(const v8bf*)&Eb[cur][row + (((4+quad) ^ X))*8];
        }
        #pragma unroll
        for (int nt = 0; nt < 4; ++nt) {
            const int q = wq*64 + nt*16 + l15;
            v8bf pf0 = *(const v8bf*)&Ps[q*64 + ((quad     ^ X))*8];
            v8bf pf1 = *(const v8bf*)&Ps[q*64 + (((4+quad) ^ X))*8];
            #pragma unroll
            for (int mt = 0; mt < 4; ++mt) {
                o[mt][nt] = __builtin_amdgcn_mfma_f32_16x16x32_bf16(ef[mt][0], pf0, o[mt][nt], 0, 0, 0);
                o[mt][nt] = __builtin_amdgcn_mfma_f32_16x16x32_bf16(ef[mt][1], pf1, o[mt][nt], 0, 0, 0);
            }
        }

        if (pre) {
            #pragma unroll
            for (int r = 0; r < 4; ++r) {
                uint2 w = { cvtpk(kr[r].x, kr[r].y), cvtpk(kr[r].z, kr[r].w) };
                *(uint2*)&Kb[nb][kwoff[r]] = w;
            }
            __syncthreads();      // drains prefetch issued a full compute-phase ago
        }
        nb ^= 1;
    }

    // ---- Z: reduce across quads ----
    #pragma unroll
    for (int nt = 0; nt < 4; ++nt) {
        float z = zacc[nt];
        z += __shfl_xor(z, 16, 64);
        z += __shfl_xor(z, 32, 64);
        if (quad == 0)
            Zpart[((size_t)c*T_TOK + tbase + nt*16 + l15)*NH + h] = z;
    }
    // ---- store O^T as bf16 (lane has 4 consecutive d per (mt,nt)) ----
    #pragma unroll
    for (int nt = 0; nt < 4; ++nt) {
        const int t = tbase + nt*16 + l15;
        unsigned short* np = Npart + (((size_t)c*T_TOK + t)*NH + h)*HD;
        #pragma unroll
        for (int mt = 0; mt < 4; ++mt) {
            v4f ov = o[mt][nt];
            uint2 w = { cvtpk(ov[0], ov[1]), cvtpk(ov[2], ov[3]) };
            *(uint2*)&np[mt*16 + quad*4] = w;
        }
    }
}

// ---------------------------------------------------------------------------
// Kernel 4: out[t, h*64+d] = sum_c N[c,t,h,d] / sum_c Z[c,t,h]   (4 elems/thr)
// ---------------------------------------------------------------------------
__global__ void combine_kernel(const unsigned short* __restrict__ Npart,
                               const float* __restrict__ Zpart,
                               float* __restrict__ out) {
    const int idx = (blockIdx.x*256 + threadIdx.x)*4;  // over T_TOK*CEMB
    const int t = idx / CEMB;
    const int rem = idx % CEMB;
    const int h = rem >> 6, d = rem & 63;
    float n0 = 0.f, n1 = 0.f, n2 = 0.f, n3 = 0.f, z = 0.f;
    #pragma unroll
    for (int c = 0; c < NC; ++c) {
        uint2 u = *(const uint2*)&Npart[(((size_t)c*T_TOK + t)*NH + h)*HD + d];
        n0 += bf2f((unsigned short)(u.x & 0xffffu));
        n1 += bf2f((unsigned short)(u.x >> 16));
        n2 += bf2f((unsigned short)(u.y & 0xffffu));
        n3 += bf2f((unsigned short)(u.y >> 16));
        z  += Zpart[((size_t)c*T_TOK + t)*NH + h];
    }
    const float rz = 1.0f / z;
    float4 o = { n0*rz, n1*rz, n2*rz, n3*rz };
    *(float4*)&out[idx] = o;
}

extern "C" void kernel_launch(void* const* d_in, const int* in_sizes, int n_in,
                              void* d_out, int out_size, void* d_ws, size_t ws_size,
                              hipStream_t stream) {
    const float* x     = (const float*)d_in[0];
    const float* Wf    = (const float*)d_in[1];
    const float* bf    = (const float*)d_in[2];
    const float* Wv    = (const float*)d_in[3];
    const float* temps = (const float*)d_in[4];
    const float* E     = (const float*)d_in[5];
    float* out = (float*)d_out;

    // workspace layout (bytes):
    //   Npart bf16: NC*512*12*64*2  = 15,728,640
    //   Zpart f32 : NC*512*12*4     =    491,520
    //   Qb    bf16: 12*512*64*2     =    786,432
    //   ET    bf16: 12*64*32000*2   = 49,152,000   (total ~66.2 MB)
    char* ws = (char*)d_ws;
    unsigned short* Npart = (unsigned short*)ws;
    float*          Zpart = (float*)(ws + 15728640);
    unsigned short* Qb    = (unsigned short*)(ws + 16220160);
    unsigned short* ET    = (unsigned short*)(ws + 17006592);

    e_transpose   <<<dim3(NV/64, NH),         256, 0, stream>>>(E, ET);
    ffn_kernel    <<<dim3(T_TOK/4, NH),       256, 0, stream>>>(x, Wf, bf, temps, Qb);
    flash_mfma    <<<dim3(NC*2*NH),           256, 0, stream>>>(Qb, Wv, ET, Npart, Zpart);
    combine_kernel<<<dim3((T_TOK*CEMB)/1024), 256, 0, stream>>>(Npart, Zpart, out);
}

// Round 4
// 299.849 us; speedup vs baseline: 1.3053x; 1.0475x over previous
//
#include <hip/hip_runtime.h>
#include <hip/hip_bf16.h>
#include <cstddef>

// Problem constants (fixed by setup_inputs)
#define T_TOK 512
#define NH    12
#define HD    64
#define NV    32000
#define CEMB  768
#define NC    20          // vocab chunks: grid = NC*2*NH = 480 = single round
#define VC    (NV/NC)     // 1600 rows per chunk
#define NSUB  (VC/64)     // 25 subtiles of 64 rows
#define QTILE 256         // queries per block (2 q-groups cover T=512)
#define LOG2E 1.44269504088896340736f

typedef short v8bf  __attribute__((ext_vector_type(8)));   // 8 bf16 = 4 VGPRs
typedef float v16f  __attribute__((ext_vector_type(16)));  // 32x32 MFMA C/D
typedef unsigned uv4 __attribute__((ext_vector_type(4)));

__device__ __forceinline__ unsigned short f2bf(float f) {
    unsigned u = __float_as_uint(f);
    u += 0x7fffu + ((u >> 16) & 1u);            // RNE
    return (unsigned short)(u >> 16);
}
// v_cvt_pk_bf16_f32: lo=bf16(a), hi=bf16(b), RNE — 1 instr vs ~9 emulated.
__device__ __forceinline__ unsigned cvtpk(float a, float b) {
    unsigned r;
    asm("v_cvt_pk_bf16_f32 %0, %1, %2" : "=v"(r) : "v"(a), "v"(b));
    return r;
}
// v_permlane32_swap_b32 x, y: x' = {x[0:31], y[0:31]}, y' = {x[32:63], y[32:63]}
__device__ __forceinline__ void pl32swap(unsigned &x, unsigned &y) {
    asm("v_permlane32_swap_b32 %0, %1" : "+v"(x), "+v"(y));
}
__device__ __forceinline__ float bf2f(unsigned short u) {
    return __uint_as_float(((unsigned)u) << 16);
}
// async global->LDS, 16B/lane; LDS dst = wave-uniform base + lane*16
__device__ __forceinline__ void gld16(const void* g, void* l) {
    __builtin_amdgcn_global_load_lds(
        (const __attribute__((address_space(1))) unsigned*)g,
        (__attribute__((address_space(3))) unsigned*)l, 16, 0, 0);
}

// ---------------------------------------------------------------------------
// Kernel 1: Qb[h][t][d] (bf16) = (x . W_ffn^T + b) * LOG2E / tau  (fp32 math)
// ---------------------------------------------------------------------------
__global__ __launch_bounds__(256) void ffn_kernel(
        const float* __restrict__ x, const float* __restrict__ Wf,
        const float* __restrict__ bf, const float* __restrict__ temps,
        unsigned short* __restrict__ Qb) {
    const int h = blockIdx.y;
    const int tl = threadIdx.x >> 6, e = threadIdx.x & 63;
    const int t = blockIdx.x * 4 + tl;
    __shared__ float xs[4][HD];
    xs[tl][e] = x[t*CEMB + h*HD + e];
    __syncthreads();
    const float4* w4  = (const float4*)(Wf + (size_t)(h*HD + e)*HD);
    const float4* xs4 = (const float4*)xs[tl];
    float acc = bf[h*HD + e];
    #pragma unroll
    for (int i = 0; i < HD/4; ++i) {
        float4 a = xs4[i], b = w4[i];
        acc += a.x*b.x + a.y*b.y + a.z*b.z + a.w*b.w;
    }
    float tau = temps[h]; tau = (tau < 0.1f) ? 0.1f : tau;
    Qb[((size_t)h*T_TOK + t)*HD + e] = f2bf(acc * LOG2E / tau);
}

// ---------------------------------------------------------------------------
// Kernel 2: E (V,768) fp32  ->  ET[h][d][v] bf16 (v contiguous), per 64-v tile.
// ---------------------------------------------------------------------------
__global__ __launch_bounds__(256) void e_transpose(const float* __restrict__ E,
                                                   unsigned short* __restrict__ ET) {
    const int v0 = blockIdx.x * 64, h = blockIdx.y;
    const int tid = threadIdx.x;
    __shared__ float Ts[64*65];                 // [d][v], stride 65
    #pragma unroll
    for (int r = 0; r < 4; ++r) {
        int f = tid + 256*r, v = f >> 4, d4 = f & 15;
        float4 e4 = *(const float4*)&E[(size_t)(v0 + v)*CEMB + h*HD + d4*4];
        Ts[(d4*4+0)*65 + v] = e4.x;
        Ts[(d4*4+1)*65 + v] = e4.y;
        Ts[(d4*4+2)*65 + v] = e4.z;
        Ts[(d4*4+3)*65 + v] = e4.w;
    }
    __syncthreads();
    #pragma unroll
    for (int r = 0; r < 2; ++r) {
        int u = tid + 256*r, d = u >> 3, c16 = u & 7;
        const float* row = &Ts[d*65 + c16*8];
        uint4 w;
        w.x = cvtpk(row[0], row[1]);
        w.y = cvtpk(row[2], row[3]);
        w.z = cvtpk(row[4], row[5]);
        w.w = cvtpk(row[6], row[7]);
        *(uint4*)&ET[(size_t)(h*64 + d)*NV + v0 + c16*8] = w;
    }
}

// ---------------------------------------------------------------------------
// Kernel 3: MFMA flash, 32x32x16 shape, P kept IN REGISTERS via
// v_permlane32_swap (no Ps LDS, no A->B LDS round-trip).
// 8 waves x 32 q-rows (512 thr, QTILE=256). LDS = Kb+Eb dbuf = 32 KB.
// launch_bounds(512,4) caps VGPR<=128 -> 2 blocks/CU = 16 waves/CU (2x R3).
// Phase A: S^T tile (v x q) = K.Q^T via mfma(A=K, B=Q): D col=lane&31=q,
//   row = 4*hi + (r&3) + 8*(r>>2) = v (m74/m101 layout). exp2 in-place.
// P-word shuffle: W[g][u] = cvtpk(p[4g+2u], p[4g+2u+1]) (v-pair 4hi+8g+2u);
//   (x',y') = permlane32_swap(W[2c][u], W[2c+1][u]) gives B-fragment words
//   w[u] = x', w[2+u] = y' for the k16-chunk c of this v-tile — all lanes.
// Phase B: O^T (d x q) += E^T.P via mfma(A=E^T, B=pf).
// XCD-pairing remap kept from R3 (FETCH 147->75 MB proven).
// ---------------------------------------------------------------------------
__global__ __launch_bounds__(512, 4) void flash_mfma(
        const unsigned short* __restrict__ Qb, const float* __restrict__ Wv,
        const unsigned short* __restrict__ ET, unsigned short* __restrict__ Npart,
        float* __restrict__ Zpart) {
    // ---- XCD-pairing remap: g and g+8 share (c,h), differ in qg ----
    const int g    = blockIdx.x;            // 0..479
    const int xcd  = g & 7, slot = g >> 3;  // slot 0..59
    const int qg   = slot & 1;
    const int p    = (slot >> 1)*8 + xcd;   // pair index 0..239
    const int c    = p % NC;
    const int h    = p / NC;

    const int tid  = threadIdx.x;
    const int wq   = tid >> 6;              // wave id 0..7: q range [wq*32, +32)
    const int lane = tid & 63;
    const int l31  = lane & 31, hi = lane >> 5;

    __shared__ unsigned short Kb[2][64*64];   // K subtile  [v][d], swizzled
    __shared__ unsigned short Eb[2][64*64];   // E^T subtile [d][v], swizzled

    const int tbase = qg*QTILE + wq*32;

    // ---- Q fragments (B-operand, resident): lane holds Q[q=tbase+l31][d=k16*16+hi*8..]
    v8bf qf[4];
    #pragma unroll
    for (int k16 = 0; k16 < 4; ++k16)
        qf[k16] = *(const v8bf*)&Qb[((size_t)h*T_TOK + tbase + l31)*HD
                                    + k16*16 + hi*8];

    v16f o0, o1;
    #pragma unroll
    for (int r = 0; r < 16; ++r) { o0[r] = 0.f; o1[r] = 0.f; }
    float zacc = 0.f;

    // ---- staging addressing (loop-invariant): wave stages 8 rows of K and E
    // K: row kv = wq*8 + (lane>>3), lane covers d = (lane&7)*8..+7 (2 float4),
    //    written as ONE swizzled ds_write_b128 (group (lane&7) ^ (kv&7)).
    const int kv = wq*8 + (lane >> 3);
    const float* kgl = Wv + ((size_t)h*NV + (size_t)c*VC + kv)*HD + (lane & 7)*8;
    const int kwoff = kv*64 + (((lane & 7) ^ (lane >> 3)))*8;
    // E: ONE gld16/wave: rows d = wq*8 + (lane>>3), pre-swizzled source group
    const unsigned short* eg = ET + (size_t)(h*64 + wq*8 + (lane >> 3))*NV
                                  + (size_t)c*VC + (((lane & 7) ^ (lane >> 3)))*8;

    // ---- prologue: stage subtile 0 into buf 0 ----
    {
        gld16(eg, &Eb[0][(wq*8)*64]);
        float4 a = *(const float4*)(kgl);
        float4 b = *(const float4*)(kgl + 4);
        uv4 w = { cvtpk(a.x,a.y), cvtpk(a.z,a.w), cvtpk(b.x,b.y), cvtpk(b.z,b.w) };
        *(uv4*)&Kb[0][kwoff] = w;
        __syncthreads();
    }

    int nb = 1;                                  // buffer being filled
    for (int s = 0; s < NSUB; ++s) {
        const int cur = nb ^ 1;                  // buffer being computed on
        const bool pre = (s + 1 < NSUB);
        float4 ka, kb2;
        if (pre) {
            gld16(eg + (s+1)*64, &Eb[nb][(wq*8)*64]);
            ka  = *(const float4*)(kgl + (size_t)(s+1)*4096);
            kb2 = *(const float4*)(kgl + (size_t)(s+1)*4096 + 4);
        }

        // ---- phase A: S'^T = K.Q^T (log2 domain), P=exp2, in-reg shuffle ----
        uv4 pfw[4];                              // B-fragment words per k16
        #pragma unroll
        for (int vt = 0; vt < 2; ++vt) {
            v8bf kf[4];
            #pragma unroll
            for (int k16 = 0; k16 < 4; ++k16) {
                const int row = vt*32 + l31;
                kf[k16] = *(const v8bf*)&Kb[cur][row*64 + ((k16*2 + hi) ^ (row & 7))*8];
            }
            v16f sa;
            #pragma unroll
            for (int r = 0; r < 16; ++r) sa[r] = 0.f;
            #pragma unroll
            for (int k16 = 0; k16 < 4; ++k16)
                sa = __builtin_amdgcn_mfma_f32_32x32x16_bf16(kf[k16], qf[k16], sa, 0, 0, 0);
            unsigned W[8];
            #pragma unroll
            for (int gi = 0; gi < 4; ++gi) {
                float pa = exp2f(sa[4*gi+0]), pb = exp2f(sa[4*gi+1]);
                float pc = exp2f(sa[4*gi+2]), pd = exp2f(sa[4*gi+3]);
                zacc += (pa + pb) + (pc + pd);
                W[2*gi+0] = cvtpk(pa, pb);
                W[2*gi+1] = cvtpk(pc, pd);
            }
            // k16-chunk c=0 of this v-tile: words from W[0..3]
            unsigned x0 = W[0], y0 = W[2];  pl32swap(x0, y0);
            unsigned x1 = W[1], y1 = W[3];  pl32swap(x1, y1);
            pfw[vt*2 + 0] = (uv4){ x0, x1, y0, y1 };
            // k16-chunk c=1: words from W[4..7]
            unsigned x2 = W[4], y2 = W[6];  pl32swap(x2, y2);
            unsigned x3 = W[5], y3 = W[7];  pl32swap(x3, y3);
            pfw[vt*2 + 1] = (uv4){ x2, x3, y2, y3 };
        }

        // ---- phase B: O^T += E^T . P (P in regs, no barrier) ----
        #pragma unroll
        for (int dt = 0; dt < 2; ++dt) {
            v8bf ef[4];
            #pragma unroll
            for (int k16 = 0; k16 < 4; ++k16) {
                const int row = dt*32 + l31;
                ef[k16] = *(const v8bf*)&Eb[cur][row*64 + ((k16*2 + hi) ^ (row & 7))*8];
            }
            v16f oo = dt ? o1 : o0;
            #pragma unroll
            for (int k16 = 0; k16 < 4; ++k16)
                oo = __builtin_amdgcn_mfma_f32_32x32x16_bf16(
                        ef[k16], __builtin_bit_cast(v8bf, pfw[k16]), oo, 0, 0, 0);
            if (dt) o1 = oo; else o0 = oo;
        }

        if (pre) {
            uv4 w = { cvtpk(ka.x,ka.y), cvtpk(ka.z,ka.w),
                      cvtpk(kb2.x,kb2.y), cvtpk(kb2.z,kb2.w) };
            *(uv4*)&Kb[nb][kwoff] = w;
            __syncthreads();      // drains prefetch issued a full compute-phase ago
        }
        nb ^= 1;
    }

    // ---- Z: reduce across lane halves (col q = l31 in both halves) ----
    zacc += __shfl_xor(zacc, 32, 64);
    if (hi == 0)
        Zpart[((size_t)c*T_TOK + tbase + l31)*NH + h] = zacc;

    // ---- store O^T as bf16: d = dt*32 + 8*gi + 4*hi + (0..3), t = tbase+l31 ----
    {
        const int t = tbase + l31;
        unsigned short* np = Npart + (((size_t)c*T_TOK + t)*NH + h)*HD;
        #pragma unroll
        for (int dt = 0; dt < 2; ++dt) {
            v16f oo = dt ? o1 : o0;
            #pragma unroll
            for (int gi = 0; gi < 4; ++gi) {
                uint2 w = { cvtpk(oo[4*gi+0], oo[4*gi+1]),
                            cvtpk(oo[4*gi+2], oo[4*gi+3]) };
                *(uint2*)&np[dt*32 + gi*8 + hi*4] = w;
            }
        }
    }
}

// ---------------------------------------------------------------------------
// Kernel 4: out[t, h*64+d] = sum_c N[c,t,h,d] / sum_c Z[c,t,h]   (4 elems/thr)
// ---------------------------------------------------------------------------
__global__ void combine_kernel(const unsigned short* __restrict__ Npart,
                               const float* __restrict__ Zpart,
                               float* __restrict__ out) {
    const int idx = (blockIdx.x*256 + threadIdx.x)*4;  // over T_TOK*CEMB
    const int t = idx / CEMB;
    const int rem = idx % CEMB;
    const int h = rem >> 6, d = rem & 63;
    float n0 = 0.f, n1 = 0.f, n2 = 0.f, n3 = 0.f, z = 0.f;
    #pragma unroll
    for (int c = 0; c < NC; ++c) {
        uint2 u = *(const uint2*)&Npart[(((size_t)c*T_TOK + t)*NH + h)*HD + d];
        n0 += bf2f((unsigned short)(u.x & 0xffffu));
        n1 += bf2f((unsigned short)(u.x >> 16));
        n2 += bf2f((unsigned short)(u.y & 0xffffu));
        n3 += bf2f((unsigned short)(u.y >> 16));
        z  += Zpart[((size_t)c*T_TOK + t)*NH + h];
    }
    const float rz = 1.0f / z;
    float4 o = { n0*rz, n1*rz, n2*rz, n3*rz };
    *(float4*)&out[idx] = o;
}

extern "C" void kernel_launch(void* const* d_in, const int* in_sizes, int n_in,
                              void* d_out, int out_size, void* d_ws, size_t ws_size,
                              hipStream_t stream) {
    const float* x     = (const float*)d_in[0];
    const float* Wf    = (const float*)d_in[1];
    const float* bf    = (const float*)d_in[2];
    const float* Wv    = (const float*)d_in[3];
    const float* temps = (const float*)d_in[4];
    const float* E     = (const float*)d_in[5];
    float* out = (float*)d_out;

    // workspace layout (bytes):
    //   Npart bf16: NC*512*12*64*2  = 15,728,640
    //   Zpart f32 : NC*512*12*4     =    491,520
    //   Qb    bf16: 12*512*64*2     =    786,432
    //   ET    bf16: 12*64*32000*2   = 49,152,000   (total ~66.2 MB)
    char* ws = (char*)d_ws;
    unsigned short* Npart = (unsigned short*)ws;
    float*          Zpart = (float*)(ws + 15728640);
    unsigned short* Qb    = (unsigned short*)(ws + 16220160);
    unsigned short* ET    = (unsigned short*)(ws + 17006592);

    e_transpose   <<<dim3(NV/64, NH),         256, 0, stream>>>(E, ET);
    ffn_kernel    <<<dim3(T_TOK/4, NH),       256, 0, stream>>>(x, Wf, bf, temps, Qb);
    flash_mfma    <<<dim3(NC*2*NH),           512, 0, stream>>>(Qb, Wv, ET, Npart, Zpart);
    combine_kernel<<<dim3((T_TOK*CEMB)/1024), 256, 0, stream>>>(Npart, Zpart, out);
}